// Round 7
// baseline (102.590 us; speedup 1.0000x reference)
//
#include <hip/hip_runtime.h>
#include <hip/hip_bf16.h>

#define D 512
#define NWAY 64
#define KSHOT 16
#define NQ 8192

typedef __bf16 bf16_t;
typedef __bf16 bf16x8_t __attribute__((ext_vector_type(8)));
typedef __bf16 bf16x4_t __attribute__((ext_vector_type(4)));
typedef float  f32x4    __attribute__((ext_vector_type(4)));

typedef __attribute__((address_space(1))) const void gv_t;
typedef __attribute__((address_space(3))) void lv_t;
__device__ __forceinline__ void ld16(const void* g, void* l) {
    __builtin_amdgcn_global_load_lds((gv_t*)g, (lv_t*)l, 16, 0, 0);
}

// Bsw: [ck(8)][n(512)][seg(8)] bf16, off = ck*32768 + n*64 + ((s^(n&7))*8)
// Psw: [c(64)][pos(64)][e(8)] bf16, off = c*512 + pos*8 + (k&7),
//   pos = (s&~7)|((s&7)^(c&7)), s = k>>3  (row-swizzled, staged verbatim)

// ---------------------------------------------------------------- K_PREP
// blocks 0..127: P pair-blocks (cp=b>>2 -> classes 2cp,2cp+1; jq=b&3):
//   each W row read ONCE, dotted against BOTH cm vectors (halves W traffic)
// blocks 128..255: W -> bf16 swizzled into Bsw (4 rows/block)
__global__ __launch_bounds__(256) void k_prep(
    const float* __restrict__ sup, const float* __restrict__ W,
    const float* __restrict__ bias, bf16_t* __restrict__ Bsw,
    bf16_t* __restrict__ Psw)
{
    const int b = blockIdx.x, t = threadIdx.x;

    if (b < 128) {                         // ---- P pair-blocks
        const int cp = b >> 2, jq = b & 3;
        const int c0 = cp * 2, c1 = c0 + 1;
        __shared__ __align__(16) float cm[2][D];
        {   // cm for both classes (float2 per thread each)
            const int d = t * 2;
            float sx0 = 0.f, sy0 = 0.f, sx1 = 0.f, sy1 = 0.f;
#pragma unroll
            for (int j = 0; j < KSHOT; ++j) {
                float2 v0 = *(const float2*)(sup + (size_t)(c0 * KSHOT + j) * D + d);
                float2 v1 = *(const float2*)(sup + (size_t)(c1 * KSHOT + j) * D + d);
                sx0 += v0.x; sy0 += v0.y; sx1 += v1.x; sy1 += v1.y;
            }
            cm[0][d] = sx0 * (1.0f / KSHOT); cm[0][d + 1] = sy0 * (1.0f / KSHOT);
            cm[1][d] = sx1 * (1.0f / KSHOT); cm[1][d + 1] = sy1 * (1.0f / KSHOT);
        }
        __syncthreads();
        const int j = jq * 128 + (t >> 1);
        const int half = t & 1;
        const f32x4* wr  = (const f32x4*)(W + (size_t)j * D + half * 256);
        const f32x4* cr0 = (const f32x4*)(cm[0] + half * 256);
        const f32x4* cr1 = (const f32x4*)(cm[1] + half * 256);
        float s0 = 0.f, s1 = 0.f;
#pragma unroll 8
        for (int i = 0; i < 64; ++i) {
            f32x4 wv = wr[i], a0 = cr0[i], a1 = cr1[i];
            s0 += a0[0]*wv[0] + a0[1]*wv[1] + a0[2]*wv[2] + a0[3]*wv[3];
            s1 += a1[0]*wv[0] + a1[1]*wv[1] + a1[2]*wv[2] + a1[3]*wv[3];
        }
        s0 += __shfl_xor(s0, 1);
        s1 += __shfl_xor(s1, 1);
        if (!half) {
            const float bj = bias[j];
            const int sP = j >> 3, e = j & 7, base = sP & ~7, lo = sP & 7;
            Psw[c0 * 512 + (base | (lo ^ (c0 & 7))) * 8 + e] = (bf16_t)(s0 + bj);
            Psw[c1 * 512 + (base | (lo ^ (c1 & 7))) * 8 + e] = (bf16_t)(s1 + bj);
        }
        return;
    }

    {                                      // ---- W conversion, 4 rows/block
        const int n = (b - 128) * 4 + (t >> 6);
        const int sl = t & 63;
        const f32x4* wp = (const f32x4*)(W + (size_t)n * D + sl * 8);
        f32x4 v0 = wp[0], v1 = wp[1];
        bf16x8_t hv = { (bf16_t)v0[0], (bf16_t)v0[1], (bf16_t)v0[2], (bf16_t)v0[3],
                        (bf16_t)v1[0], (bf16_t)v1[1], (bf16_t)v1[2], (bf16_t)v1[3] };
        const int ck = sl >> 3, s = sl & 7;
        *(bf16x8_t*)(Bsw + (size_t)ck * 32768 + n * 64 + ((s ^ (n & 7)) * 8)) = hv;
    }
}

// ---------------------------------------------------------------- K_MAIN
// (R5 body — best at 99.3 — with one change: chunk-0 B-DMA issues BEFORE
// the query A-preload, so the first barrier waits on max(DMA, preload)
// instead of their sum.)
__global__ __launch_bounds__(512, 2) void k_main(
    const float* __restrict__ query, const bf16_t* __restrict__ Bsw,
    const bf16_t* __restrict__ Psw, const float* __restrict__ bias,
    float* __restrict__ out)
{
    __shared__ __align__(16) bf16_t Bb[2][32768]; // 131,072 B
    __shared__ __align__(16) bf16_t Ab[2][2048];  //   8,192 B
    __shared__ float qln[4][32];    //     512 B
    __shared__ float phs[NWAY];     //     256 B
    __shared__ float bs[512];       //   2,048 B   (total 142,080 B -> 1/CU)

    const int t = threadIdx.x, bm = blockIdx.x;

    // ---- issue chunk-0 B-DMA FIRST (critical path of first barrier)
#pragma unroll
    for (int i = 0; i < 8; ++i) {
        const int off = t * 8 + i * 4096;
        ld16(Bsw + off, &Bb[0][off]);
    }

    bs[t] = bias[t];

    const int l = t & 63, w = t >> 6;
    const int wm = w & 1, wn = w >> 1;
    const int r15 = l & 15, quad = l >> 4;

    const int xt0 = ((quad ^ (r15 & 7)) * 8);
    const int xt1 = (((4 + quad) ^ (r15 & 7)) * 8);
    const int aoff = (wm * 16 + r15) * 64;
    const int boff = (wn * 128 + r15) * 64;

    // ---- A preload: each thread owns row am, 4 cols per chunk, all 8 chunks
    const int am = t >> 4;                 // 0..31
    const int ac4 = t & 15;
    const int a_lds = am * 64 + (((ac4 >> 1) ^ (am & 7)) * 8) + (ac4 & 1) * 4;
    const float* aqp = query + (size_t)(bm * 32 + am) * D + ac4 * 4;

    bf16x4_t areg[8];
#pragma unroll
    for (int ck = 0; ck < 8; ++ck) {
        f32x4 v = *(const f32x4*)(aqp + ck * 64);
        areg[ck] = (bf16x4_t){ (bf16_t)v[0], (bf16_t)v[1], (bf16_t)v[2], (bf16_t)v[3] };
    }

    f32x4 acc[8];
#pragma unroll
    for (int i = 0; i < 8; ++i) acc[i] = (f32x4){0.f, 0.f, 0.f, 0.f};

    *(bf16x4_t*)(&Ab[0][a_lds]) = areg[0];
    __syncthreads();   // drains vmcnt(0)+lgkmcnt(0): chunk 0 ready

    // ---- main loop: issue-next / compute-current / one barrier per chunk
#pragma unroll
    for (int ck = 0; ck < 8; ++ck) {
        const int cur = ck & 1;
        if (ck < 7) {
            const int nxt = cur ^ 1;
            const size_t sb = (size_t)(ck + 1) * 32768;
#pragma unroll
            for (int i = 0; i < 8; ++i) {
                const int off = t * 8 + i * 4096;
                ld16(Bsw + sb + off, &Bb[nxt][off]);
            }
            *(bf16x4_t*)(&Ab[nxt][a_lds]) = areg[ck + 1];
        } else {
            // chunk-7 stage slot: DMA the P tile into Bb[0] (chunk-6 reads
            // of Bb[0] completed at the ck==6 barrier; chunk 7 uses Bb[1])
#pragma unroll
            for (int i = 0; i < 8; ++i) {
                const int off = t * 8 + i * 4096;
                ld16(Psw + off, &Bb[0][off]);
            }
        }

        bf16x8_t a0 = *(const bf16x8_t*)(&Ab[cur][aoff + xt0]);
        bf16x8_t a1 = *(const bf16x8_t*)(&Ab[cur][aoff + xt1]);
#pragma unroll
        for (int tt = 0; tt < 8; ++tt) {
            bf16x8_t b0 = *(const bf16x8_t*)(&Bb[cur][boff + tt * 1024 + xt0]);
            bf16x8_t b1 = *(const bf16x8_t*)(&Bb[cur][boff + tt * 1024 + xt1]);
            acc[tt] = __builtin_amdgcn_mfma_f32_16x16x32_bf16(a0, b0, acc[tt], 0, 0, 0);
            acc[tt] = __builtin_amdgcn_mfma_f32_16x16x32_bf16(a1, b1, acc[tt], 0, 0, 0);
        }

        if (ck < 7) __syncthreads();
    }
    __syncthreads();   // drains P DMA; all chunk-7 reads of Bb[1] done

    // ---- epilogue part 1: eq = acc + bias -> qt partials + E' transpose ----
    // E' (32 rows x 512 k, bf16, row-swizzled) lives in Bb[1][0..16384)
    bf16_t* Ex = &Bb[1][0];
    float qp[4] = {0.f, 0.f, 0.f, 0.f};
#pragma unroll
    for (int tt = 0; tt < 8; ++tt) {
        const int k = wn * 128 + tt * 16 + r15;
        const int s = k >> 3, klo = k & 7;
        const float bv = bs[k];
#pragma unroll
        for (int reg = 0; reg < 4; ++reg) {
            const int row = wm * 16 + quad * 4 + reg;
            const float v = acc[tt][reg] + bv;
            qp[reg] += v * v;
            const int pos = (s & ~7) | ((s & 7) ^ (row & 7));
            Ex[row * 512 + pos * 8 + klo] = (bf16_t)v;
        }
    }
#pragma unroll
    for (int reg = 0; reg < 4; ++reg) {
        float s = qp[reg];
        s += __shfl_xor(s, 1); s += __shfl_xor(s, 2);
        s += __shfl_xor(s, 4); s += __shfl_xor(s, 8);
        if (r15 == 0) qln[wn][wm * 16 + quad * 4 + reg] = s;
    }

    // ---- ||p~||^2 from the staged bf16 P tile (swizzle-invariant) ----
    if (t < NWAY) {
        const bf16_t* pr = &Bb[0][t * 512];
        float s2 = 0.f;
#pragma unroll
        for (int i = 0; i < 64; ++i) {
            bf16x8_t v = *(const bf16x8_t*)(pr + i * 8);
#pragma unroll
            for (int e = 0; e < 8; ++e) { float f = (float)v[e]; s2 += f * f; }
        }
        phs[t] = s2;
    }
    __syncthreads();

    // ---- epilogue part 2: cross-GEMM C[32x64] = eq . P^T ----
    // wave (wm,wn): rows wm*16..+16, k-slice wn*128..+128, all 64 classes
    f32x4 cacc[4];
#pragma unroll
    for (int ct = 0; ct < 4; ++ct) cacc[ct] = (f32x4){0.f, 0.f, 0.f, 0.f};
    const bf16_t* Pl = &Bb[0][0];
#pragma unroll
    for (int kk = 0; kk < 4; ++kk) {
        const int s = wn * 16 + kk * 4 + quad;               // k>>3
        const int pos = (s & ~7) | ((s & 7) ^ (r15 & 7));    // row&7 == r15&7
        bf16x8_t af = *(const bf16x8_t*)(Ex + (wm * 16 + r15) * 512 + pos * 8);
#pragma unroll
        for (int ct = 0; ct < 4; ++ct) {
            bf16x8_t bf = *(const bf16x8_t*)(Pl + (ct * 16 + r15) * 512 + pos * 8);
            cacc[ct] = __builtin_amdgcn_mfma_f32_16x16x32_bf16(af, bf, cacc[ct], 0, 0, 0);
        }
    }

    // ---- cross-wave (wn) reduction via LDS exchange in Bb[1][16384..) ----
    f32x4* ex = (f32x4*)&Bb[1][16384];   // 32 KB region, disjoint from Ex
#pragma unroll
    for (int ct = 0; ct < 4; ++ct)
        ex[((wm * 4 + ct) * 4 + wn) * 64 + l] = cacc[ct];
    __syncthreads();

    f32x4 cf = ex[((wm * 4 + wn) * 4 + 0) * 64 + l];
#pragma unroll
    for (int wnp = 1; wnp < 4; ++wnp)
        cf = cf + ex[((wm * 4 + wn) * 4 + wnp) * 64 + l];

    // ---- write dists: qt - 2*cross + ||p~||^2 ----
#pragma unroll
    for (int reg = 0; reg < 4; ++reg) {
        const int row_local = wm * 16 + quad * 4 + reg;
        const float qt = qln[0][row_local] + qln[1][row_local] +
                         qln[2][row_local] + qln[3][row_local];
        const int rowg = bm * 32 + row_local;
        const int c = wn * 16 + r15;
        out[(size_t)rowg * NWAY + c] = qt + phs[c] - 2.0f * cf[reg];
    }
}

// ---------------------------------------------------------------- launch
extern "C" void kernel_launch(void* const* d_in, const int* in_sizes, int n_in,
                              void* d_out, int out_size, void* d_ws, size_t ws_size,
                              hipStream_t stream)
{
    const float* support = (const float*)d_in[0];
    const float* query   = (const float*)d_in[1];
    const float* W       = (const float*)d_in[2];
    const float* bias    = (const float*)d_in[3];
    float* out = (float*)d_out;

    char* ws = (char*)d_ws;
    bf16_t* Bsw = (bf16_t*)ws;                    // 524,288 B
    bf16_t* Psw = (bf16_t*)(ws + 524288);         //  65,536 B

    k_prep<<<256, 256, 0, stream>>>(support, W, bias, Bsw, Psw);
    k_main<<<256, 512, 0, stream>>>(query, Bsw, Psw, bias, out);
}

// Round 8
// 102.300 us; speedup vs baseline: 1.0028x; 1.0028x over previous
//
#include <hip/hip_runtime.h>
#include <hip/hip_bf16.h>

#define D 512
#define NWAY 64
#define KSHOT 16
#define NQ 8192

typedef __bf16 bf16_t;
typedef __bf16 bf16x8_t __attribute__((ext_vector_type(8)));
typedef __bf16 bf16x4_t __attribute__((ext_vector_type(4)));
typedef float  f32x4    __attribute__((ext_vector_type(4)));

typedef __attribute__((address_space(1))) const void gv_t;
typedef __attribute__((address_space(3))) void lv_t;
__device__ __forceinline__ void ld16(const void* g, void* l) {
    __builtin_amdgcn_global_load_lds((gv_t*)g, (lv_t*)l, 16, 0, 0);
}

// Bsw: [ck(8)][n(512)][seg(8)] bf16, off = ck*32768 + n*64 + ((s^(n&7))*8)
// Psw: [c(64)][pos(64)][e(8)] bf16, off = c*512 + pos*8 + (k&7),
//   pos = (s&~7)|((s&7)^(c&7)), s = k>>3  (row-swizzled, staged verbatim)

// ---------------------------------------------------------------- K_PREP
// (exact R5 version — proven at 99.3)
// blocks 0..255: P blocks (c=b>>2, jq=b&3): P_c[j] = cm_c.W_j + b_j -> Psw bf16
// blocks 256..383: W -> bf16 swizzled into Bsw (4 rows/block)
__global__ __launch_bounds__(256) void k_prep(
    const float* __restrict__ sup, const float* __restrict__ W,
    const float* __restrict__ bias, bf16_t* __restrict__ Bsw,
    bf16_t* __restrict__ Psw)
{
    const int b = blockIdx.x, t = threadIdx.x;

    if (b < 256) {                         // ---- P blocks
        const int c = b >> 2, jq = b & 3;
        __shared__ __align__(16) float cm[D];
        {   // cm_c = mean over shots (float2 per thread)
            const int d = t * 2;
            float sx = 0.f, sy = 0.f;
#pragma unroll
            for (int j = 0; j < KSHOT; ++j) {
                float2 v = *(const float2*)(sup + (size_t)(c * KSHOT + j) * D + d);
                sx += v.x; sy += v.y;
            }
            cm[d] = sx * (1.0f / KSHOT); cm[d + 1] = sy * (1.0f / KSHOT);
        }
        __syncthreads();
        const int j = jq * 128 + (t >> 1);
        const int half = t & 1;
        const f32x4* wr = (const f32x4*)(W + (size_t)j * D + half * 256);
        const f32x4* cr = (const f32x4*)(cm + half * 256);
        float s = 0.f;
#pragma unroll 8
        for (int i = 0; i < 64; ++i) {
            f32x4 a = cr[i], wv = wr[i];
            s += a[0]*wv[0] + a[1]*wv[1] + a[2]*wv[2] + a[3]*wv[3];
        }
        s += __shfl_xor(s, 1);
        if (!half) {
            const float v = s + bias[j];
            const int sP = j >> 3;
            const int pos = (sP & ~7) | ((sP & 7) ^ (c & 7));
            Psw[c * 512 + pos * 8 + (j & 7)] = (bf16_t)v;
        }
        return;
    }

    {                                      // ---- W conversion, 4 rows/block
        const int n = (b - 256) * 4 + (t >> 6);
        const int sl = t & 63;
        const f32x4* wp = (const f32x4*)(W + (size_t)n * D + sl * 8);
        f32x4 v0 = wp[0], v1 = wp[1];
        bf16x8_t hv = { (bf16_t)v0[0], (bf16_t)v0[1], (bf16_t)v0[2], (bf16_t)v0[3],
                        (bf16_t)v1[0], (bf16_t)v1[1], (bf16_t)v1[2], (bf16_t)v1[3] };
        const int ck = sl >> 3, s = sl & 7;
        *(bf16x8_t*)(Bsw + (size_t)ck * 32768 + n * 64 + ((s ^ (n & 7)) * 8)) = hv;
    }
}

// ---------------------------------------------------------------- K_MAIN
// 256 blocks (128 row-tiles x 2 col-halves) x 512 thr. BM=64, BN=256:
// per-block staged bytes halved (288 KB) with all 256 CUs busy. Each
// half-block computes a PARTIAL distance over its 256 cols (qt, cross,
// ||p||^2 all decompose over j) and atomicAdd-combines onto zeroed out.
__global__ __launch_bounds__(512, 2) void k_main(
    const float* __restrict__ query, const bf16_t* __restrict__ Bsw,
    const bf16_t* __restrict__ Psw, const float* __restrict__ bias,
    float* __restrict__ out)
{
    __shared__ __align__(16) bf16_t Bb[2][16384]; // 65,536 B (32 KB each)
    __shared__ __align__(16) bf16_t Ab[2][4096];  // 16,384 B (8 KB each)
    __shared__ float qln[4][64];    //   1,024 B
    __shared__ float phs[NWAY];     //     256 B
    __shared__ float bs[256];       //   1,024 B   (total ~84 KB)

    const int t = threadIdx.x;
    const int bm = blockIdx.x >> 1;        // row-tile (64 query rows)
    const int h  = blockIdx.x & 1;         // col half (256 of 512 cols)

    if (t < 256) bs[t] = bias[h * 256 + t];

    const int l = t & 63, w = t >> 6;
    const int wm = w & 1, wn = w >> 1;
    const int r15 = l & 15, quad = l >> 4;

    const int xt0 = ((quad ^ (r15 & 7)) * 8);
    const int xt1 = (((4 + quad) ^ (r15 & 7)) * 8);
    const int aoff0 = (wm * 32 + r15) * 64;
    const int aoff1 = (wm * 32 + 16 + r15) * 64;
    const int boff = (wn * 64 + r15) * 64;

    // ---- A preload FIRST (oldest in vmcnt queue -> cvt doesn't drain DMA)
    const int am = t >> 3;                 // 0..63
    const int as = t & 7;
    const int a_lds = am * 64 + ((as ^ (am & 7)) * 8);
    const float* aqp = query + (size_t)(bm * 64 + am) * D + as * 8;

    bf16x8_t areg[8];
#pragma unroll
    for (int ck = 0; ck < 8; ++ck) {
        f32x4 v0 = *(const f32x4*)(aqp + ck * 64);
        f32x4 v1 = *(const f32x4*)(aqp + ck * 64 + 4);
        areg[ck] = (bf16x8_t){ (bf16_t)v0[0], (bf16_t)v0[1], (bf16_t)v0[2], (bf16_t)v0[3],
                               (bf16_t)v1[0], (bf16_t)v1[1], (bf16_t)v1[2], (bf16_t)v1[3] };
    }

    f32x4 acc[2][4];
#pragma unroll
    for (int rt = 0; rt < 2; ++rt)
#pragma unroll
        for (int i = 0; i < 4; ++i) acc[rt][i] = (f32x4){0.f, 0.f, 0.f, 0.f};

    // ---- prologue: stage chunk 0 (B half: 32 KB) into buffer 0
    const int hbase = h * 16384;           // elem offset of this col-half
#pragma unroll
    for (int i = 0; i < 4; ++i) {
        const int off = t * 8 + i * 4096;
        ld16(Bsw + hbase + off, &Bb[0][off]);
    }
    *(bf16x8_t*)(&Ab[0][a_lds]) = areg[0];
    __syncthreads();   // drains vmcnt(0)+lgkmcnt(0): chunk 0 ready

    // ---- main loop: issue-next / compute-current / one barrier per chunk
#pragma unroll
    for (int ck = 0; ck < 8; ++ck) {
        const int cur = ck & 1;
        if (ck < 7) {
            const int nxt = cur ^ 1;
            const size_t sb = (size_t)(ck + 1) * 32768 + hbase;
#pragma unroll
            for (int i = 0; i < 4; ++i) {
                const int off = t * 8 + i * 4096;
                ld16(Bsw + sb + off, &Bb[nxt][off]);
            }
            *(bf16x8_t*)(&Ab[nxt][a_lds]) = areg[ck + 1];
        } else {
            // chunk-7 stage slot: DMA the P k-half (32 KB) into Bb[0]
            // dest Pb[c][j] = Bb[0][c*256+j]; src = Psw[c*512 + h*256 + j]
#pragma unroll
            for (int i = 0; i < 4; ++i) {
                const int off = t * 8 + i * 4096;
                const int c = off >> 8, j = off & 255;
                ld16(Psw + c * 512 + h * 256 + j, &Bb[0][off]);
            }
        }

        bf16x8_t a00 = *(const bf16x8_t*)(&Ab[cur][aoff0 + xt0]);
        bf16x8_t a01 = *(const bf16x8_t*)(&Ab[cur][aoff0 + xt1]);
        bf16x8_t a10 = *(const bf16x8_t*)(&Ab[cur][aoff1 + xt0]);
        bf16x8_t a11 = *(const bf16x8_t*)(&Ab[cur][aoff1 + xt1]);
#pragma unroll
        for (int tt = 0; tt < 4; ++tt) {
            bf16x8_t b0 = *(const bf16x8_t*)(&Bb[cur][boff + tt * 1024 + xt0]);
            bf16x8_t b1 = *(const bf16x8_t*)(&Bb[cur][boff + tt * 1024 + xt1]);
            acc[0][tt] = __builtin_amdgcn_mfma_f32_16x16x32_bf16(a00, b0, acc[0][tt], 0, 0, 0);
            acc[0][tt] = __builtin_amdgcn_mfma_f32_16x16x32_bf16(a01, b1, acc[0][tt], 0, 0, 0);
            acc[1][tt] = __builtin_amdgcn_mfma_f32_16x16x32_bf16(a10, b0, acc[1][tt], 0, 0, 0);
            acc[1][tt] = __builtin_amdgcn_mfma_f32_16x16x32_bf16(a11, b1, acc[1][tt], 0, 0, 0);
        }

        if (ck < 7) __syncthreads();
    }
    __syncthreads();   // drains P DMA; all chunk-7 reads of Bb[1] done

    // ---- epilogue part 1: eq = acc + bias -> qt partials + E' transpose ----
    // E' (64 rows x 256 k, bf16, row-swizzled) = all of Bb[1]
    bf16_t* Ex = &Bb[1][0];
    float qp[2][4] = {{0.f,0.f,0.f,0.f},{0.f,0.f,0.f,0.f}};
#pragma unroll
    for (int tt = 0; tt < 4; ++tt) {
        const int k = wn * 64 + tt * 16 + r15;       // local col in [0,256)
        const int s = k >> 3, klo = k & 7;
        const float bv = bs[k];
#pragma unroll
        for (int rt = 0; rt < 2; ++rt)
#pragma unroll
        for (int reg = 0; reg < 4; ++reg) {
            const int row = wm * 32 + rt * 16 + quad * 4 + reg;
            const float v = acc[rt][tt][reg] + bv;
            qp[rt][reg] += v * v;
            const int pos = (s & ~7) | ((s & 7) ^ (row & 7));
            Ex[row * 256 + pos * 8 + klo] = (bf16_t)v;
        }
    }
#pragma unroll
    for (int rt = 0; rt < 2; ++rt)
#pragma unroll
    for (int reg = 0; reg < 4; ++reg) {
        float s = qp[rt][reg];
        s += __shfl_xor(s, 1); s += __shfl_xor(s, 2);
        s += __shfl_xor(s, 4); s += __shfl_xor(s, 8);
        if (r15 == 0) qln[wn][wm * 32 + rt * 16 + quad * 4 + reg] = s;
    }

    // ---- partial ||p~||^2 over this k-half (swizzle-invariant) ----
    if (t < NWAY) {
        const bf16_t* pr = &Bb[0][t * 256];
        float s2 = 0.f;
#pragma unroll
        for (int i = 0; i < 32; ++i) {
            bf16x8_t v = *(const bf16x8_t*)(pr + i * 8);
#pragma unroll
            for (int e = 0; e < 8; ++e) { float f = (float)v[e]; s2 += f * f; }
        }
        phs[t] = s2;
    }
    __syncthreads();

    // ---- epilogue part 2: cross-GEMM C[64x64] = E' . P^T, full k-half ----
    // wave w: row-tile rt2 = w>>1 (16 rows), class-tiles (w&1)*2 + {0,1}
    const int rt2 = w >> 1, cg = w & 1;
    f32x4 cacc[2];
    cacc[0] = (f32x4){0.f, 0.f, 0.f, 0.f};
    cacc[1] = (f32x4){0.f, 0.f, 0.f, 0.f};
    const bf16_t* Pl = &Bb[0][0];
#pragma unroll
    for (int kk = 0; kk < 8; ++kk) {
        const int s = kk * 4 + quad;                      // k>>3 in [0,32)
        const int posA = (s & ~7) | ((s & 7) ^ (r15 & 7)); // row&7 == r15&7
        bf16x8_t af = *(const bf16x8_t*)(Ex + (rt2 * 16 + r15) * 256 + posA * 8);
#pragma unroll
        for (int j = 0; j < 2; ++j) {
            bf16x8_t bf = *(const bf16x8_t*)(Pl + ((cg * 2 + j) * 16 + r15) * 256 + posA * 8);
            cacc[j] = __builtin_amdgcn_mfma_f32_16x16x32_bf16(af, bf, cacc[j], 0, 0, 0);
        }
    }

    // ---- atomicAdd partial dists: qt_h - 2*cross_h + ph_h ----
#pragma unroll
    for (int reg = 0; reg < 4; ++reg) {
        const int row_local = rt2 * 16 + quad * 4 + reg;
        const float qt = qln[0][row_local] + qln[1][row_local] +
                         qln[2][row_local] + qln[3][row_local];
        const int rowg = bm * 64 + row_local;
#pragma unroll
        for (int j = 0; j < 2; ++j) {
            const int c = (cg * 2 + j) * 16 + r15;
            atomicAdd(&out[(size_t)rowg * NWAY + c],
                      qt + phs[c] - 2.0f * cacc[j][reg]);
        }
    }
}

// ---------------------------------------------------------------- launch
extern "C" void kernel_launch(void* const* d_in, const int* in_sizes, int n_in,
                              void* d_out, int out_size, void* d_ws, size_t ws_size,
                              hipStream_t stream)
{
    const float* support = (const float*)d_in[0];
    const float* query   = (const float*)d_in[1];
    const float* W       = (const float*)d_in[2];
    const float* bias    = (const float*)d_in[3];
    float* out = (float*)d_out;

    char* ws = (char*)d_ws;
    bf16_t* Bsw = (bf16_t*)ws;                    // 524,288 B
    bf16_t* Psw = (bf16_t*)(ws + 524288);         //  65,536 B

    hipMemsetAsync(out, 0, (size_t)NQ * NWAY * sizeof(float), stream);
    k_prep<<<384, 256, 0, stream>>>(support, W, bias, Bsw, Psw);
    k_main<<<256, 512, 0, stream>>>(query, Bsw, Psw, bias, out);
}

// Round 9
// 99.473 us; speedup vs baseline: 1.0313x; 1.0284x over previous
//
#include <hip/hip_runtime.h>
#include <hip/hip_bf16.h>

#define D 512
#define NWAY 64
#define KSHOT 16
#define NQ 8192

typedef __bf16 bf16_t;
typedef __bf16 bf16x8_t __attribute__((ext_vector_type(8)));
typedef __bf16 bf16x4_t __attribute__((ext_vector_type(4)));
typedef float  f32x4    __attribute__((ext_vector_type(4)));

typedef __attribute__((address_space(1))) const void gv_t;
typedef __attribute__((address_space(3))) void lv_t;
__device__ __forceinline__ void ld16(const void* g, void* l) {
    __builtin_amdgcn_global_load_lds((gv_t*)g, (lv_t*)l, 16, 0, 0);
}

// Bsw: [ck(8)][n(512)][seg(8)] bf16, off = ck*32768 + n*64 + ((s^(n&7))*8)
// Psw: [c(64)][pos(64)][e(8)] bf16, off = c*512 + pos*8 + (k&7),
//   pos = (s&~7)|((s&7)^(c&7)), s = k>>3  (row-swizzled, staged verbatim)

// ---------------------------------------------------------------- K_PREP
// blocks 0..255: P blocks (c=b>>2, jq=b&3): P_c[j] = cm_c.W_j + b_j -> Psw bf16
// blocks 256..383: W -> bf16 swizzled into Bsw (4 rows/block)
__global__ __launch_bounds__(256) void k_prep(
    const float* __restrict__ sup, const float* __restrict__ W,
    const float* __restrict__ bias, bf16_t* __restrict__ Bsw,
    bf16_t* __restrict__ Psw)
{
    const int b = blockIdx.x, t = threadIdx.x;

    if (b < 256) {                         // ---- P blocks
        const int c = b >> 2, jq = b & 3;
        __shared__ __align__(16) float cm[D];
        {   // cm_c = mean over shots (float2 per thread)
            const int d = t * 2;
            float sx = 0.f, sy = 0.f;
#pragma unroll
            for (int j = 0; j < KSHOT; ++j) {
                float2 v = *(const float2*)(sup + (size_t)(c * KSHOT + j) * D + d);
                sx += v.x; sy += v.y;
            }
            cm[d] = sx * (1.0f / KSHOT); cm[d + 1] = sy * (1.0f / KSHOT);
        }
        __syncthreads();
        const int j = jq * 128 + (t >> 1);
        const int half = t & 1;
        const f32x4* wr = (const f32x4*)(W + (size_t)j * D + half * 256);
        const f32x4* cr = (const f32x4*)(cm + half * 256);
        float s = 0.f;
#pragma unroll 8
        for (int i = 0; i < 64; ++i) {
            f32x4 a = cr[i], wv = wr[i];
            s += a[0]*wv[0] + a[1]*wv[1] + a[2]*wv[2] + a[3]*wv[3];
        }
        s += __shfl_xor(s, 1);
        if (!half) {
            const float v = s + bias[j];
            const int sP = j >> 3;
            const int pos = (sP & ~7) | ((sP & 7) ^ (c & 7));
            Psw[c * 512 + pos * 8 + (j & 7)] = (bf16_t)v;
        }
        return;
    }

    {                                      // ---- W conversion, 4 rows/block
        const int n = (b - 256) * 4 + (t >> 6);
        const int sl = t & 63;
        const f32x4* wp = (const f32x4*)(W + (size_t)n * D + sl * 8);
        f32x4 v0 = wp[0], v1 = wp[1];
        bf16x8_t hv = { (bf16_t)v0[0], (bf16_t)v0[1], (bf16_t)v0[2], (bf16_t)v0[3],
                        (bf16_t)v1[0], (bf16_t)v1[1], (bf16_t)v1[2], (bf16_t)v1[3] };
        const int ck = sl >> 3, s = sl & 7;
        *(bf16x8_t*)(Bsw + (size_t)ck * 32768 + n * 64 + ((s ^ (n & 7)) * 8)) = hv;
    }
}

// ---------------------------------------------------------------- K_MAIN
// 256 blocks x 512 thr, 1 block/CU. Main GEMM (8 chunks, 512 cols) with
// double-buffered DMA; chunk 7's stage slot DMAs the 64KB Psw tile into
// Bb[0] (replacing the old G staging byte-for-byte). Epilogue: eq = acc+b
// -> bf16 transpose to LDS -> in-block cross-GEMM eq.P^T (128 MFMA) ->
// cross-wave reduce -> dist = qt - 2*cross + ||p~||^2.
__global__ __launch_bounds__(512, 2) void k_main(
    const float* __restrict__ query, const bf16_t* __restrict__ Bsw,
    const bf16_t* __restrict__ Psw, const float* __restrict__ bias,
    float* __restrict__ out)
{
    __shared__ __align__(16) bf16_t Bb[2][32768]; // 131,072 B
    __shared__ __align__(16) bf16_t Ab[2][2048];  //   8,192 B
    __shared__ float qln[4][32];    //     512 B
    __shared__ float phs[NWAY];     //     256 B
    __shared__ float bs[512];       //   2,048 B   (total 142,080 B -> 1/CU)

    const int t = threadIdx.x, bm = blockIdx.x;
    bs[t] = bias[t];

    const int l = t & 63, w = t >> 6;
    const int wm = w & 1, wn = w >> 1;
    const int r15 = l & 15, quad = l >> 4;

    const int xt0 = ((quad ^ (r15 & 7)) * 8);
    const int xt1 = (((4 + quad) ^ (r15 & 7)) * 8);
    const int aoff = (wm * 16 + r15) * 64;
    const int boff = (wn * 128 + r15) * 64;

    // ---- A preload: each thread owns row am, 4 cols per chunk, all 8 chunks
    const int am = t >> 4;                 // 0..31
    const int ac4 = t & 15;
    const int a_lds = am * 64 + (((ac4 >> 1) ^ (am & 7)) * 8) + (ac4 & 1) * 4;
    const float* aqp = query + (size_t)(bm * 32 + am) * D + ac4 * 4;

    bf16x4_t areg[8];
#pragma unroll
    for (int ck = 0; ck < 8; ++ck) {
        f32x4 v = *(const f32x4*)(aqp + ck * 64);
        areg[ck] = (bf16x4_t){ (bf16_t)v[0], (bf16_t)v[1], (bf16_t)v[2], (bf16_t)v[3] };
    }

    f32x4 acc[8];
#pragma unroll
    for (int i = 0; i < 8; ++i) acc[i] = (f32x4){0.f, 0.f, 0.f, 0.f};

    // ---- prologue: stage chunk 0 into buffer 0
    {
#pragma unroll
        for (int i = 0; i < 8; ++i) {
            const int off = t * 8 + i * 4096;
            ld16(Bsw + off, &Bb[0][off]);
        }
        *(bf16x4_t*)(&Ab[0][a_lds]) = areg[0];
    }
    __syncthreads();   // drains vmcnt(0)+lgkmcnt(0): chunk 0 ready

    // ---- main loop: issue-next / compute-current / one barrier per chunk
#pragma unroll
    for (int ck = 0; ck < 8; ++ck) {
        const int cur = ck & 1;
        if (ck < 7) {
            const int nxt = cur ^ 1;
            const size_t sb = (size_t)(ck + 1) * 32768;
#pragma unroll
            for (int i = 0; i < 8; ++i) {
                const int off = t * 8 + i * 4096;
                ld16(Bsw + sb + off, &Bb[nxt][off]);
            }
            *(bf16x4_t*)(&Ab[nxt][a_lds]) = areg[ck + 1];
        } else {
            // chunk-7 stage slot: DMA the P tile into Bb[0] (chunk 6's
            // reads of Bb[0] completed at the ck==6 barrier; chunk 7
            // computes from Bb[1])
#pragma unroll
            for (int i = 0; i < 8; ++i) {
                const int off = t * 8 + i * 4096;
                ld16(Psw + off, &Bb[0][off]);
            }
        }

        bf16x8_t a0 = *(const bf16x8_t*)(&Ab[cur][aoff + xt0]);
        bf16x8_t a1 = *(const bf16x8_t*)(&Ab[cur][aoff + xt1]);
#pragma unroll
        for (int tt = 0; tt < 8; ++tt) {
            bf16x8_t b0 = *(const bf16x8_t*)(&Bb[cur][boff + tt * 1024 + xt0]);
            bf16x8_t b1 = *(const bf16x8_t*)(&Bb[cur][boff + tt * 1024 + xt1]);
            acc[tt] = __builtin_amdgcn_mfma_f32_16x16x32_bf16(a0, b0, acc[tt], 0, 0, 0);
            acc[tt] = __builtin_amdgcn_mfma_f32_16x16x32_bf16(a1, b1, acc[tt], 0, 0, 0);
        }

        if (ck < 7) __syncthreads();
    }
    __syncthreads();   // drains P DMA; all chunk-7 reads of Bb[1] done

    // ---- epilogue part 1: eq = acc + bias -> qt partials + E' transpose ----
    // E' (32 rows x 512 k, bf16, row-swizzled) lives in Bb[1][0..16384)
    bf16_t* Ex = &Bb[1][0];
    float qp[4] = {0.f, 0.f, 0.f, 0.f};
#pragma unroll
    for (int tt = 0; tt < 8; ++tt) {
        const int k = wn * 128 + tt * 16 + r15;
        const int s = k >> 3, klo = k & 7;
        const float bv = bs[k];
#pragma unroll
        for (int reg = 0; reg < 4; ++reg) {
            const int row = wm * 16 + quad * 4 + reg;
            const float v = acc[tt][reg] + bv;
            qp[reg] += v * v;
            const int pos = (s & ~7) | ((s & 7) ^ (row & 7));
            Ex[row * 512 + pos * 8 + klo] = (bf16_t)v;
        }
    }
#pragma unroll
    for (int reg = 0; reg < 4; ++reg) {
        float s = qp[reg];
        s += __shfl_xor(s, 1); s += __shfl_xor(s, 2);
        s += __shfl_xor(s, 4); s += __shfl_xor(s, 8);
        if (r15 == 0) qln[wn][wm * 16 + quad * 4 + reg] = s;
    }

    // ---- ||p~||^2 from the staged bf16 P tile (swizzle-invariant) ----
    if (t < NWAY) {
        const bf16_t* pr = &Bb[0][t * 512];
        float s2 = 0.f;
#pragma unroll
        for (int i = 0; i < 64; ++i) {
            bf16x8_t v = *(const bf16x8_t*)(pr + i * 8);
#pragma unroll
            for (int e = 0; e < 8; ++e) { float f = (float)v[e]; s2 += f * f; }
        }
        phs[t] = s2;
    }
    __syncthreads();

    // ---- epilogue part 2: cross-GEMM C[32x64] = eq . P^T ----
    // wave (wm,wn): rows wm*16..+16, k-slice wn*128..+128, all 64 classes
    f32x4 cacc[4];
#pragma unroll
    for (int ct = 0; ct < 4; ++ct) cacc[ct] = (f32x4){0.f, 0.f, 0.f, 0.f};
    const bf16_t* Pl = &Bb[0][0];
#pragma unroll
    for (int kk = 0; kk < 4; ++kk) {
        const int s = wn * 16 + kk * 4 + quad;               // k>>3
        const int pos = (s & ~7) | ((s & 7) ^ (r15 & 7));    // row&7 == r15&7
        bf16x8_t af = *(const bf16x8_t*)(Ex + (wm * 16 + r15) * 512 + pos * 8);
#pragma unroll
        for (int ct = 0; ct < 4; ++ct) {
            bf16x8_t bf = *(const bf16x8_t*)(Pl + (ct * 16 + r15) * 512 + pos * 8);
            cacc[ct] = __builtin_amdgcn_mfma_f32_16x16x32_bf16(af, bf, cacc[ct], 0, 0, 0);
        }
    }

    // ---- cross-wave (wn) reduction via LDS exchange in Bb[1][16384..) ----
    f32x4* ex = (f32x4*)&Bb[1][16384];   // 32 KB region, disjoint from Ex
#pragma unroll
    for (int ct = 0; ct < 4; ++ct)
        ex[((wm * 4 + ct) * 4 + wn) * 64 + l] = cacc[ct];
    __syncthreads();

    f32x4 cf = ex[((wm * 4 + wn) * 4 + 0) * 64 + l];
#pragma unroll
    for (int wnp = 1; wnp < 4; ++wnp)
        cf = cf + ex[((wm * 4 + wn) * 4 + wnp) * 64 + l];

    // ---- write dists: qt - 2*cross + ||p~||^2 ----
#pragma unroll
    for (int reg = 0; reg < 4; ++reg) {
        const int row_local = wm * 16 + quad * 4 + reg;
        const float qt = qln[0][row_local] + qln[1][row_local] +
                         qln[2][row_local] + qln[3][row_local];
        const int rowg = bm * 32 + row_local;
        const int c = wn * 16 + r15;
        out[(size_t)rowg * NWAY + c] = qt + phs[c] - 2.0f * cf[reg];
    }
}

// ---------------------------------------------------------------- launch
extern "C" void kernel_launch(void* const* d_in, const int* in_sizes, int n_in,
                              void* d_out, int out_size, void* d_ws, size_t ws_size,
                              hipStream_t stream)
{
    const float* support = (const float*)d_in[0];
    const float* query   = (const float*)d_in[1];
    const float* W       = (const float*)d_in[2];
    const float* bias    = (const float*)d_in[3];
    float* out = (float*)d_out;

    char* ws = (char*)d_ws;
    bf16_t* Bsw = (bf16_t*)ws;                    // 524,288 B
    bf16_t* Psw = (bf16_t*)(ws + 524288);         //  65,536 B

    k_prep<<<384, 256, 0, stream>>>(support, W, bias, Bsw, Psw);
    k_main<<<256, 512, 0, stream>>>(query, Bsw, Psw, bias, out);
}